// Round 1
// baseline (731.098 us; speedup 1.0000x reference)
//
#include <hip/hip_runtime.h>
#include <hip/hip_bf16.h>
#include <hip/hip_fp16.h>

// Problem constants
#define GG 8
#define GPP 16
#define AA 65
#define HH 128
#define CC 128
#define NN 2
#define WW 128
#define BB 256            // N*W
#define EDC_ 10
#define OFF_ 2

__device__ __forceinline__ void rz_taps(int o, float scale, int in_size,
                                        int& ia, int& ib, float& f) {
  // jax.image.resize 'linear' antialias=False: sample at (o+0.5)*scale-0.5,
  // 2-tap triangle with boundary renormalization == clamped-index lerp.
  float pos = (o + 0.5f) * scale - 0.5f;
  float fl = floorf(pos);
  int i0 = (int)fl;
  f = pos - fl;
  ia = i0 < 0 ? 0 : i0;
  int i1 = i0 + 1;
  ib = i1 > (in_size - 1) ? (in_size - 1) : i1;
}

__device__ __forceinline__ float gelu_exact(float v) {
  return 0.5f * v * (1.0f + erff(v * 0.70710678118654752f));
}

#define RSBN 0.99999500003749977f  // 1/sqrt(1+1e-5)

// ---------- A: base_relative (32,255,255) -> relA (32,65,65) ----------
__global__ void k_relA(const float* __restrict__ base, float* __restrict__ relA) {
  int idx = blockIdx.x * 256 + threadIdx.x;
  if (idx >= 32 * AA * AA) return;
  int j = idx % AA;
  int r = idx / AA;
  int i = r % AA;
  int c = r / AA;
  int ia, ib, ja, jb; float fi, fj;
  rz_taps(i, 255.0f / 65.0f, 255, ia, ib, fi);
  rz_taps(j, 255.0f / 65.0f, 255, ja, jb, fj);
  const float* S = base + (size_t)c * 255 * 255;
  float v = (1.0f - fi) * ((1.0f - fj) * S[ia * 255 + ja] + fj * S[ia * 255 + jb])
          + fi * ((1.0f - fj) * S[ib * 255 + ja] + fj * S[ib * 255 + jb]);
  relA[idx] = v;
}

// ---------- B: v_emb (relA ch 16..31, 65x65) -> v_emb_h (16,128,128) ----------
__global__ void k_vembh(const float* __restrict__ relA, float* __restrict__ vembh) {
  int idx = blockIdx.x * 256 + threadIdx.x;  // 16*128*128 = 262144
  int xj = idx & 127;
  int r = idx >> 7;
  int yi = r & 127;
  int c = r >> 7;
  int ia, ib, ja, jb; float fi, fj;
  rz_taps(yi, 65.0f / 128.0f, 65, ia, ib, fi);
  rz_taps(xj, 65.0f / 128.0f, 65, ja, jb, fj);
  const float* S = relA + (size_t)(16 + c) * (AA * AA);
  float v = (1.0f - fi) * ((1.0f - fj) * S[ia * AA + ja] + fj * S[ia * AA + jb])
          + fi * ((1.0f - fj) * S[ib * AA + ja] + fj * S[ib * AA + jb]);
  vembh[idx] = v;
}

// ---------- C: qkv GEMM + BN. out[n][o][i*128+w] = sum_c w_qkv[o][c]*x[n][c][i][w] ----------
__global__ void k_qkv(const float* __restrict__ x, const float* __restrict__ wq,
                      const float* __restrict__ bg, const float* __restrict__ bb,
                      float* __restrict__ out) {
  // grid (128 p-tiles, 4 o-tiles, 2 n), block 256
  const int pb = blockIdx.x * 128;
  const int ob = blockIdx.y * 64;
  const int n = blockIdx.z;
  __shared__ float wsm[64 * 16];
  __shared__ float xs[16 * 128];
  const int t = threadIdx.x;
  const int tx = t & 31, ty = t >> 5;
  float acc[8][4] = {};
  const float* xn_ = x + (size_t)n * CC * 16384;
  for (int k0 = 0; k0 < 128; k0 += 16) {
    #pragma unroll
    for (int l = 0; l < 4; ++l) {
      int idx = t + l * 256;
      wsm[idx] = wq[(ob + (idx >> 4)) * 128 + k0 + (idx & 15)];
    }
    #pragma unroll
    for (int l = 0; l < 8; ++l) {
      int idx = t + l * 256;
      int kk = idx >> 7, pp = idx & 127;
      xs[idx] = xn_[(size_t)(k0 + kk) * 16384 + pb + pp];
    }
    __syncthreads();
    #pragma unroll
    for (int kk = 0; kk < 16; ++kk) {
      float4 xv = *(const float4*)&xs[kk * 128 + tx * 4];
      #pragma unroll
      for (int r = 0; r < 8; ++r) {
        float wv = wsm[(ty * 8 + r) * 16 + kk];
        acc[r][0] += wv * xv.x; acc[r][1] += wv * xv.y;
        acc[r][2] += wv * xv.z; acc[r][3] += wv * xv.w;
      }
    }
    __syncthreads();
  }
  #pragma unroll
  for (int r = 0; r < 8; ++r) {
    int o = ob + ty * 8 + r;
    float sc = bg[o] * RSBN, sh = bb[o];
    float4 v;
    v.x = acc[r][0] * sc + sh; v.y = acc[r][1] * sc + sh;
    v.z = acc[r][2] * sc + sh; v.w = acc[r][3] * sc + sh;
    *(float4*)&out[((size_t)(n * 256 + o)) * 16384 + pb + tx * 4] = v;
  }
}

// ---------- D: downsample qkv along i (128->65), split into qa/ka/va ----------
__global__ void k_down(const float* __restrict__ qkv, float* __restrict__ qa,
                       float* __restrict__ ka, float* __restrict__ va) {
  int idx = blockIdx.x * 256 + threadIdx.x;  // 256*8*32*65 = 4,259,840
  if (idx >= BB * GG * 32 * AA) return;
  int a = idx % AA;
  int r = idx / AA;
  int cc = r % 32; r /= 32;
  int g = r % 8;
  int b = r / 8;
  int n = b >> 7, w = b & 127;
  int o = g * 32 + cc;
  int ia, ib; float f;
  rz_taps(a, 128.0f / 65.0f, 128, ia, ib, f);
  const float* src = qkv + ((size_t)(n * 256 + o)) * 16384 + w;
  float v = (1.0f - f) * src[ia * 128] + f * src[ib * 128];
  int bg = b * 8 + g;
  if (cc < 8)       qa[(bg * 8 + cc) * AA + a] = v;
  else if (cc < 16) ka[(bg * 8 + (cc - 8)) * AA + a] = v;
  else              va[(bg * 16 + (cc - 16)) * AA + a] = v;
}

// ---------- D2: v_h = upsample va along a (65->128) ----------
__global__ void k_vh(const float* __restrict__ va, float* __restrict__ vh) {
  int idx = blockIdx.x * 256 + threadIdx.x;  // 256*8*16*128 = 4,194,304
  int j = idx & 127;
  int r = idx >> 7;  // bg*16 + c
  int ia, ib; float f;
  rz_taps(j, 65.0f / 128.0f, 65, ia, ib, f);
  const float* src = va + (size_t)r * AA;
  vh[idx] = (1.0f - f) * src[ia] + f * src[ib];
}

// ---------- E: simA[b,g,i,j] = BN-combined qk + qr + kr at 65x65 ----------
__global__ void k_sim(const float* __restrict__ qa, const float* __restrict__ ka,
                      const float* __restrict__ relA, const float* __restrict__ sg,
                      const float* __restrict__ sb, float* __restrict__ simA) {
  int bg = blockIdx.x;
  int g = bg & 7;
  __shared__ float qs[8 * AA], ks[8 * AA];
  int t = threadIdx.x;
  for (int l = t; l < 8 * AA; l += 256) {
    qs[l] = qa[(size_t)bg * (8 * AA) + l];
    ks[l] = ka[(size_t)bg * (8 * AA) + l];
  }
  __syncthreads();
  float sqk = sg[g] * RSBN, sqr = sg[8 + g] * RSBN, skr = sg[16 + g] * RSBN;
  float badd = sb[g] + sb[8 + g] + sb[16 + g];
  for (int l = t; l < AA * AA; l += 256) {
    int i = l / AA, j = l % AA;
    float qk = 0.f, qr = 0.f, kr = 0.f;
    #pragma unroll
    for (int c = 0; c < 8; ++c) {
      float qv = qs[c * AA + i], kv = ks[c * AA + j];
      qk += qv * kv;
      qr += qv * relA[(size_t)c * (AA * AA) + i * AA + j];
      kr += kv * relA[(size_t)(8 + c) * (AA * AA) + j * AA + i];
    }
    simA[(size_t)bg * (AA * AA) + l] = sqk * qk + sqr * qr + skr * kr + badd;
  }
}

// ---------- F: fused 65->128 resize + softmax + sv/sve + bn_out + pair-sum -> y ----------
__global__ void k_attn(const float* __restrict__ simA, const float* __restrict__ vh,
                       const float* __restrict__ vembh, const float* __restrict__ og,
                       const float* __restrict__ ob, float* __restrict__ y) {
  int bg = blockIdx.x;
  int b = bg >> 3, g = bg & 7;
  int n = b >> 7, w = b & 127;
  __shared__ float Ss[AA * AA];        // 16.9 KB
  __shared__ float vhs[16 * 128];      // 8 KB
  __shared__ __half Ps[128 * 130];     // 33.3 KB, padded stride vs bank conflicts
  int t = threadIdx.x;
  for (int l = t; l < AA * AA; l += 256) Ss[l] = simA[(size_t)bg * (AA * AA) + l];
  for (int l = t; l < 2048; l += 256) vhs[l] = vh[(size_t)bg * 2048 + l];
  __syncthreads();
  if (t < 128) {
    int i = t;
    int ia, ib; float fi;
    rz_taps(i, 65.0f / 128.0f, 65, ia, ib, fi);
    const float* r0 = Ss + ia * AA;
    const float* r1 = Ss + ib * AA;
    float mx = -1e30f;
    for (int j = 0; j < 128; ++j) {
      int ja, jb; float fj;
      rz_taps(j, 65.0f / 128.0f, 65, ja, jb, fj);
      float v = (1.0f - fi) * ((1.0f - fj) * r0[ja] + fj * r0[jb])
              + fi * ((1.0f - fj) * r1[ja] + fj * r1[jb]);
      mx = fmaxf(mx, v);
    }
    float sum = 0.f;
    for (int j = 0; j < 128; ++j) {
      int ja, jb; float fj;
      rz_taps(j, 65.0f / 128.0f, 65, ja, jb, fj);
      float v = (1.0f - fi) * ((1.0f - fj) * r0[ja] + fj * r0[jb])
              + fi * ((1.0f - fj) * r1[ja] + fj * r1[jb]);
      float e = __expf(v - mx);
      sum += e;
      Ps[i * 130 + j] = __float2half(e);
    }
    float inv = 1.0f / sum;
    for (int j = 0; j < 128; ++j) {
      Ps[i * 130 + j] = __float2half(__half2float(Ps[i * 130 + j]) * inv);
    }
  }
  __syncthreads();
  #pragma unroll
  for (int l = 0; l < 8; ++l) {
    int oi = t + l * 256;  // 0..2047
    int c = oi >> 7, i = oi & 127;
    const float* ve = vembh + ((size_t)c * 128 + i) * 128;
    float sv = 0.f, sve = 0.f;
    for (int j = 0; j < 128; ++j) {
      float p = __half2float(Ps[i * 130 + j]);
      sv += p * vhs[c * 128 + j];
      sve += p * ve[j];
    }
    int c2 = g * 16 + c;
    int o0 = 2 * c2;
    float val = og[o0] * RSBN * sv + ob[o0] + og[o0 + 1] * RSBN * sve + ob[o0 + 1];
    y[(((size_t)n * 128 + c2) * 128 + i) * 128 + w] = val;
  }
}

// ---------- G: shift-concat + instance-norm stats -> xo, per-(n,c) scale/shift ----------
__global__ void k_shift_stats(const float* __restrict__ y, const float* __restrict__ inw,
                              const float* __restrict__ inb, float* __restrict__ xo,
                              float* __restrict__ ss) {
  int nc = blockIdx.x;  // 256
  int n = nc >> 7, c = nc & 127;
  int t = threadIdx.x;
  const float* yn = y + (size_t)n * 128 * 16384;
  int sc_ch = c, dh = 0, dw = 0;
  if (c < 10)      { sc_ch = c;      dw = -2; }
  else if (c < 20) { sc_ch = c - 10; dw = 2; }
  else if (c < 30) { sc_ch = c - 20; dh = -2; }
  else if (c < 40) { sc_ch = c - 30; dh = 2; }
  const float* src = yn + (size_t)sc_ch * 16384;
  float* dst = xo + (size_t)nc * 16384;
  float s = 0.f, s2 = 0.f;
  for (int l = 0; l < 64; ++l) {
    int idx = t + l * 256;
    int h = idx >> 7, w = idx & 127;
    int hs = h + dh, ws_ = w + dw;
    float v = 0.f;
    if (hs >= 0 && hs < 128 && ws_ >= 0 && ws_ < 128) v = src[hs * 128 + ws_];
    dst[idx] = v;
    s += v; s2 += v * v;
  }
  __shared__ float rs[256], rs2[256];
  rs[t] = s; rs2[t] = s2;
  __syncthreads();
  for (int st = 128; st > 0; st >>= 1) {
    if (t < st) { rs[t] += rs[t + st]; rs2[t] += rs2[t + st]; }
    __syncthreads();
  }
  if (t == 0) {
    float mean = rs[0] * (1.0f / 16384.0f);
    float var = rs2[0] * (1.0f / 16384.0f) - mean * mean;
    float scale = inw[c] * rsqrtf(var + 1e-5f);
    ss[2 * nc] = scale;
    ss[2 * nc + 1] = inb[c] - mean * scale;
  }
}

// ---------- H1: h1 = gelu(W1 . xn), norm applied on load ----------
__global__ void k_mlp1(const float* __restrict__ xo, const float* __restrict__ ss,
                       const float* __restrict__ w1, float* __restrict__ h1) {
  // grid (128, 8, 2)
  const int pb = blockIdx.x * 128;
  const int ob = blockIdx.y * 64;
  const int n = blockIdx.z;
  __shared__ float wsm[64 * 16];
  __shared__ float xs[16 * 128];
  const int t = threadIdx.x;
  const int tx = t & 31, ty = t >> 5;
  float acc[8][4] = {};
  const float* xn_ = xo + (size_t)n * 128 * 16384;
  for (int k0 = 0; k0 < 128; k0 += 16) {
    #pragma unroll
    for (int l = 0; l < 4; ++l) {
      int idx = t + l * 256;
      wsm[idx] = w1[(ob + (idx >> 4)) * 128 + k0 + (idx & 15)];
    }
    #pragma unroll
    for (int l = 0; l < 8; ++l) {
      int idx = t + l * 256;
      int kk = idx >> 7, pp = idx & 127;
      int ch = k0 + kk;
      float sc = ss[2 * (n * 128 + ch)];
      float sh = ss[2 * (n * 128 + ch) + 1];
      xs[idx] = xn_[(size_t)ch * 16384 + pb + pp] * sc + sh;
    }
    __syncthreads();
    #pragma unroll
    for (int kk = 0; kk < 16; ++kk) {
      float4 xv = *(const float4*)&xs[kk * 128 + tx * 4];
      #pragma unroll
      for (int r = 0; r < 8; ++r) {
        float wv = wsm[(ty * 8 + r) * 16 + kk];
        acc[r][0] += wv * xv.x; acc[r][1] += wv * xv.y;
        acc[r][2] += wv * xv.z; acc[r][3] += wv * xv.w;
      }
    }
    __syncthreads();
  }
  #pragma unroll
  for (int r = 0; r < 8; ++r) {
    int o = ob + ty * 8 + r;
    float4 v;
    v.x = gelu_exact(acc[r][0]); v.y = gelu_exact(acc[r][1]);
    v.z = gelu_exact(acc[r][2]); v.w = gelu_exact(acc[r][3]);
    *(float4*)&h1[((size_t)(n * 512 + o)) * 16384 + pb + tx * 4] = v;
  }
}

// ---------- H2: out = W2 . h1 + identity(y) ----------
__global__ void k_mlp2(const float* __restrict__ h1, const float* __restrict__ w2,
                       const float* __restrict__ y, float* __restrict__ out) {
  // grid (128, 2, 2)
  const int pb = blockIdx.x * 128;
  const int ob = blockIdx.y * 64;
  const int n = blockIdx.z;
  __shared__ float wsm[64 * 16];
  __shared__ float xs[16 * 128];
  const int t = threadIdx.x;
  const int tx = t & 31, ty = t >> 5;
  float acc[8][4] = {};
  const float* hn = h1 + (size_t)n * 512 * 16384;
  for (int k0 = 0; k0 < 512; k0 += 16) {
    #pragma unroll
    for (int l = 0; l < 4; ++l) {
      int idx = t + l * 256;
      wsm[idx] = w2[(ob + (idx >> 4)) * 512 + k0 + (idx & 15)];
    }
    #pragma unroll
    for (int l = 0; l < 8; ++l) {
      int idx = t + l * 256;
      int kk = idx >> 7, pp = idx & 127;
      xs[idx] = hn[(size_t)(k0 + kk) * 16384 + pb + pp];
    }
    __syncthreads();
    #pragma unroll
    for (int kk = 0; kk < 16; ++kk) {
      float4 xv = *(const float4*)&xs[kk * 128 + tx * 4];
      #pragma unroll
      for (int r = 0; r < 8; ++r) {
        float wv = wsm[(ty * 8 + r) * 16 + kk];
        acc[r][0] += wv * xv.x; acc[r][1] += wv * xv.y;
        acc[r][2] += wv * xv.z; acc[r][3] += wv * xv.w;
      }
    }
    __syncthreads();
  }
  #pragma unroll
  for (int r = 0; r < 8; ++r) {
    int o = ob + ty * 8 + r;
    size_t base = ((size_t)(n * 128 + o)) * 16384 + pb + tx * 4;
    float4 yv = *(const float4*)&y[base];
    float4 v;
    v.x = acc[r][0] + yv.x; v.y = acc[r][1] + yv.y;
    v.z = acc[r][2] + yv.z; v.w = acc[r][3] + yv.w;
    *(float4*)&out[base] = v;
  }
}

extern "C" void kernel_launch(void* const* d_in, const int* in_sizes, int n_in,
                              void* d_out, int out_size, void* d_ws, size_t ws_size,
                              hipStream_t stream) {
  const float* x        = (const float*)d_in[0];
  const float* w_qkv    = (const float*)d_in[1];
  const float* bn_qkv_g = (const float*)d_in[2];
  const float* bn_qkv_b = (const float*)d_in[3];
  const float* bn_sim_g = (const float*)d_in[4];
  const float* bn_sim_b = (const float*)d_in[5];
  const float* bn_out_g = (const float*)d_in[6];
  const float* bn_out_b = (const float*)d_in[7];
  const float* in_w     = (const float*)d_in[8];
  const float* in_b     = (const float*)d_in[9];
  const float* mlp_w1   = (const float*)d_in[10];
  const float* mlp_w2   = (const float*)d_in[11];
  const float* base_rel = (const float*)d_in[12];
  float* Wp = (float*)d_ws;

  float* relA  = Wp + 0;         // 135,200  (pad to 135,424)
  float* vembh = Wp + 135424;    // 262,144
  float* qa    = Wp + 397568;    // 1,064,960
  float* ka    = Wp + 1462528;   // 1,064,960
  float* va    = Wp + 2527488;   // 2,129,920
  float* vh    = Wp + 4657408;   // 4,194,304
  float* yb    = Wp + 8851712;   // 4,194,304
  float* ssb   = Wp + 13046016;  // 1,024
  float* xo    = Wp + 13047040;  // 4,194,304
  float* qkv   = Wp + 17241344;  // 8,388,608 (dead after k_down)
  float* simA  = Wp + 17241344;  // 8,652,800 (overlays qkv; dead after k_attn)
  float* h1    = Wp + 17241344;  // 16,777,216 (overlays simA)
  // peak: 34,018,560 floats = 136.1 MB

  k_relA<<<dim3(529), dim3(256), 0, stream>>>(base_rel, relA);
  k_vembh<<<dim3(1024), dim3(256), 0, stream>>>(relA, vembh);
  k_qkv<<<dim3(128, 4, 2), dim3(256), 0, stream>>>(x, w_qkv, bn_qkv_g, bn_qkv_b, qkv);
  k_down<<<dim3(16640), dim3(256), 0, stream>>>(qkv, qa, ka, va);
  k_vh<<<dim3(16384), dim3(256), 0, stream>>>(va, vh);
  k_sim<<<dim3(2048), dim3(256), 0, stream>>>(qa, ka, relA, bn_sim_g, bn_sim_b, simA);
  k_attn<<<dim3(2048), dim3(256), 0, stream>>>(simA, vh, vembh, bn_out_g, bn_out_b, yb);
  k_shift_stats<<<dim3(256), dim3(256), 0, stream>>>(yb, in_w, in_b, xo, ssb);
  k_mlp1<<<dim3(128, 8, 2), dim3(256), 0, stream>>>(xo, ssb, mlp_w1, h1);
  k_mlp2<<<dim3(128, 2, 2), dim3(256), 0, stream>>>(h1, mlp_w2, yb, (float*)d_out);
}

// Round 2
// 515.769 us; speedup vs baseline: 1.4175x; 1.4175x over previous
//
#include <hip/hip_runtime.h>
#include <hip/hip_bf16.h>
#include <hip/hip_fp16.h>

// Problem constants
#define GG 8
#define GPP 16
#define AA 65
#define HH 128
#define CC 128
#define NN 2
#define WW 128
#define BB 256            // N*W
#define EDC_ 10
#define OFF_ 2

__device__ __forceinline__ void rz_taps(int o, float scale, int in_size,
                                        int& ia, int& ib, float& f) {
  // jax.image.resize 'linear' antialias=False: sample at (o+0.5)*scale-0.5,
  // 2-tap triangle with boundary renormalization == clamped-index lerp.
  float pos = (o + 0.5f) * scale - 0.5f;
  float fl = floorf(pos);
  int i0 = (int)fl;
  f = pos - fl;
  ia = i0 < 0 ? 0 : i0;
  int i1 = i0 + 1;
  ib = i1 > (in_size - 1) ? (in_size - 1) : i1;
}

__device__ __forceinline__ float gelu_exact(float v) {
  return 0.5f * v * (1.0f + erff(v * 0.70710678118654752f));
}

#define RSBN 0.99999500003749977f  // 1/sqrt(1+1e-5)

// ---------- A: base_relative (32,255,255) -> relA (32,65,65) ----------
__global__ void k_relA(const float* __restrict__ base, float* __restrict__ relA) {
  int idx = blockIdx.x * 256 + threadIdx.x;
  if (idx >= 32 * AA * AA) return;
  int j = idx % AA;
  int r = idx / AA;
  int i = r % AA;
  int c = r / AA;
  int ia, ib, ja, jb; float fi, fj;
  rz_taps(i, 255.0f / 65.0f, 255, ia, ib, fi);
  rz_taps(j, 255.0f / 65.0f, 255, ja, jb, fj);
  const float* S = base + (size_t)c * 255 * 255;
  float v = (1.0f - fi) * ((1.0f - fj) * S[ia * 255 + ja] + fj * S[ia * 255 + jb])
          + fi * ((1.0f - fj) * S[ib * 255 + ja] + fj * S[ib * 255 + jb]);
  relA[idx] = v;
}

// ---------- B: veI[c][a][i] = i-upsampled (65->128) v_emb on the 65-j grid ----------
__global__ void k_vei(const float* __restrict__ relA, float* __restrict__ veI) {
  int idx = blockIdx.x * 256 + threadIdx.x;  // 16*65*128 = 133,120
  if (idx >= 16 * AA * 128) return;
  int i = idx & 127;
  int r = idx >> 7;           // c*65 + a
  int a = r % AA, c = r / AA;
  int ia, ib; float fi;
  rz_taps(i, 65.0f / 128.0f, 65, ia, ib, fi);
  const float* S = relA + (size_t)(16 + c) * (AA * AA);
  veI[idx] = (1.0f - fi) * S[ia * AA + a] + fi * S[ib * AA + a];
}

// ---------- C: qkv GEMM + BN. out[n][o][i*128+w] = sum_c w_qkv[o][c]*x[n][c][i][w] ----------
__global__ void k_qkv(const float* __restrict__ x, const float* __restrict__ wq,
                      const float* __restrict__ bg, const float* __restrict__ bb,
                      float* __restrict__ out) {
  const int pb = blockIdx.x * 128;
  const int ob = blockIdx.y * 64;
  const int n = blockIdx.z;
  __shared__ float wsm[64 * 16];
  __shared__ float xs[16 * 128];
  const int t = threadIdx.x;
  const int tx = t & 31, ty = t >> 5;
  float acc[8][4] = {};
  const float* xn_ = x + (size_t)n * CC * 16384;
  for (int k0 = 0; k0 < 128; k0 += 16) {
    #pragma unroll
    for (int l = 0; l < 4; ++l) {
      int idx = t + l * 256;
      wsm[idx] = wq[(ob + (idx >> 4)) * 128 + k0 + (idx & 15)];
    }
    #pragma unroll
    for (int l = 0; l < 8; ++l) {
      int idx = t + l * 256;
      int kk = idx >> 7, pp = idx & 127;
      xs[idx] = xn_[(size_t)(k0 + kk) * 16384 + pb + pp];
    }
    __syncthreads();
    #pragma unroll
    for (int kk = 0; kk < 16; ++kk) {
      float4 xv = *(const float4*)&xs[kk * 128 + tx * 4];
      #pragma unroll
      for (int r = 0; r < 8; ++r) {
        float wv = wsm[(ty * 8 + r) * 16 + kk];
        acc[r][0] += wv * xv.x; acc[r][1] += wv * xv.y;
        acc[r][2] += wv * xv.z; acc[r][3] += wv * xv.w;
      }
    }
    __syncthreads();
  }
  #pragma unroll
  for (int r = 0; r < 8; ++r) {
    int o = ob + ty * 8 + r;
    float sc = bg[o] * RSBN, sh = bb[o];
    float4 v;
    v.x = acc[r][0] * sc + sh; v.y = acc[r][1] * sc + sh;
    v.z = acc[r][2] * sc + sh; v.w = acc[r][3] * sc + sh;
    *(float4*)&out[((size_t)(n * 256 + o)) * 16384 + pb + tx * 4] = v;
  }
}

// ---------- D: downsample qkv along i (128->65), split into qa/ka/va ----------
__global__ void k_down(const float* __restrict__ qkv, float* __restrict__ qa,
                       float* __restrict__ ka, float* __restrict__ va) {
  int idx = blockIdx.x * 256 + threadIdx.x;
  if (idx >= BB * GG * 32 * AA) return;
  int a = idx % AA;
  int r = idx / AA;
  int cc = r % 32; r /= 32;
  int g = r % 8;
  int b = r / 8;
  int n = b >> 7, w = b & 127;
  int o = g * 32 + cc;
  int ia, ib; float f;
  rz_taps(a, 128.0f / 65.0f, 128, ia, ib, f);
  const float* src = qkv + ((size_t)(n * 256 + o)) * 16384 + w;
  float v = (1.0f - f) * src[ia * 128] + f * src[ib * 128];
  int bg = b * 8 + g;
  if (cc < 8)       qa[(bg * 8 + cc) * AA + a] = v;
  else if (cc < 16) ka[(bg * 8 + (cc - 8)) * AA + a] = v;
  else              va[(bg * 16 + (cc - 16)) * AA + a] = v;
}

// ---------- E: simA[b,g,i,j] = BN-combined qk + qr + kr at 65x65 ----------
__global__ void k_sim(const float* __restrict__ qa, const float* __restrict__ ka,
                      const float* __restrict__ relA, const float* __restrict__ sg,
                      const float* __restrict__ sb, float* __restrict__ simA) {
  int bg = blockIdx.x;
  int g = bg & 7;
  __shared__ float qs[8 * AA], ks[8 * AA];
  int t = threadIdx.x;
  for (int l = t; l < 8 * AA; l += 256) {
    qs[l] = qa[(size_t)bg * (8 * AA) + l];
    ks[l] = ka[(size_t)bg * (8 * AA) + l];
  }
  __syncthreads();
  float sqk = sg[g] * RSBN, sqr = sg[8 + g] * RSBN, skr = sg[16 + g] * RSBN;
  float badd = sb[g] + sb[8 + g] + sb[16 + g];
  for (int l = t; l < AA * AA; l += 256) {
    int i = l / AA, j = l % AA;
    float qk = 0.f, qr = 0.f, kr = 0.f;
    #pragma unroll
    for (int c = 0; c < 8; ++c) {
      float qv = qs[c * AA + i], kv = ks[c * AA + j];
      qk += qv * kv;
      qr += qv * relA[(size_t)c * (AA * AA) + i * AA + j];
      kr += kv * relA[(size_t)(8 + c) * (AA * AA) + j * AA + i];
    }
    simA[(size_t)bg * (AA * AA) + l] = sqk * qk + sqr * qr + skr * kr + badd;
  }
}

// ---------- F: fused softmax(65->128 resize) folded to 65-grid weights + sv/sve ----------
// Pw[i][a] = sum_j softmax_row_i(S128)[j] * w_j(a); then
//   sv[c,i]  = sum_a Pw[i,a]*va65[c,a],  sve[c,i] = sum_a Pw[i,a]*veI[c,a,i]
__global__ void k_attn(const float* __restrict__ simA, const float* __restrict__ va,
                       const float* __restrict__ veI, const float* __restrict__ og,
                       const float* __restrict__ ob, float* __restrict__ y) {
  int bg = blockIdx.x;
  int b = bg >> 3, g = bg & 7;
  int n = b >> 7, w = b & 127;
  __shared__ float Ss[AA * AA];         // 16,900 B
  __shared__ __half Pws[128 * 66];      // 16,896 B (stride 66 halves = 132 B)
  __shared__ float vas[16 * AA];        // 4,160 B
  __shared__ float fjs[128];            // 512 B
  __shared__ int jabs[128];             // 512 B  (ja | jb<<16)
  int t = threadIdx.x;

  for (int l = t; l < AA * AA; l += 256) Ss[l] = simA[(size_t)bg * (AA * AA) + l];
  for (int l = t; l < 16 * AA; l += 256) vas[l] = va[(size_t)bg * (16 * AA) + l];
  { // zero Pw (as uints)
    unsigned int* pz = (unsigned int*)Pws;
    for (int l = t; l < 128 * 33; l += 256) pz[l] = 0u;
  }
  if (t < 128) {
    int ja, jb; float fj;
    rz_taps(t, 65.0f / 128.0f, 65, ja, jb, fj);
    fjs[t] = fj;
    jabs[t] = ja | (jb << 16);
  }
  __syncthreads();

  // ---- softmax + fold to Pw: 2 threads per row i ----
  {
    int i = t >> 1, h = t & 1;
    int ia, ib; float fi;
    rz_taps(i, 65.0f / 128.0f, 65, ia, ib, fi);
    const float* r0 = Ss + ia * AA;
    const float* r1 = Ss + ib * AA;
    float w1 = 1.0f - fi;
    // pass A: max over this thread's 64 columns
    float mx = -1e30f;
    #pragma unroll 8
    for (int jj = 0; jj < 64; ++jj) {
      int j = h * 64 + jj;
      int jab = jabs[j]; float fj = fjs[j];
      int ja = jab & 0xffff, jb = jab >> 16;
      float v = w1 * ((1.0f - fj) * r0[ja] + fj * r0[jb])
              + fi * ((1.0f - fj) * r1[ja] + fj * r1[jb]);
      mx = fmaxf(mx, v);
    }
    mx = fmaxf(mx, __shfl_xor(mx, 1));
    // pass B: exp + scatter into Pw (h0 owns a in [0,31], h1 owns [33,64];
    // a==32 is the only overlap -> keep in a register, combine via shuffle)
    float sum = 0.f, a32 = 0.f;
    __half* prow = &Pws[i * 66];
    #pragma unroll 4
    for (int jj = 0; jj < 64; ++jj) {
      int j = h * 64 + jj;
      int jab = jabs[j]; float fj = fjs[j];
      int ja = jab & 0xffff, jb = jab >> 16;
      float v = w1 * ((1.0f - fj) * r0[ja] + fj * r0[jb])
              + fi * ((1.0f - fj) * r1[ja] + fj * r1[jb]);
      float e = __expf(v - mx);
      sum += e;
      float c0 = e * (1.0f - fj), c1 = e * fj;
      if (ja == 32) a32 += c0;
      else prow[ja] = __float2half(__half2float(prow[ja]) + c0);
      if (jb == 32) a32 += c1;
      else prow[jb] = __float2half(__half2float(prow[jb]) + c1);
    }
    sum += __shfl_xor(sum, 1);
    a32 += __shfl_xor(a32, 1);
    float inv = 1.0f / sum;
    if (h == 0) prow[32] = __float2half(a32);
    // normalize own half of the row (h0: a 0..32, h1: a 33..64)
    int a0 = h * 33, cnt = 33 - h;
    for (int k = 0; k < cnt; ++k) {
      int a = a0 + k;
      prow[a] = __float2half(__half2float(prow[a]) * inv);
    }
  }
  __syncthreads();

  // ---- sv/sve contraction over 65 taps + bn_out + pair-sum -> y ----
  #pragma unroll
  for (int l = 0; l < 8; ++l) {
    int oi = t + l * 256;          // 0..2047
    int c = oi >> 7, i = oi & 127;
    const __half* prow = &Pws[i * 66];
    const float* vrow = &vas[c * AA];
    const float* vp = veI + (size_t)c * (AA * 128) + i;
    float sv = 0.f, sve = 0.f;
    #pragma unroll 8
    for (int k = 0; k < 32; ++k) {
      __half2 ph = *(const __half2*)(prow + 2 * k);
      float2 pf = __half22float2(ph);
      sv  += pf.x * vrow[2 * k]     + pf.y * vrow[2 * k + 1];
      sve += pf.x * vp[(2 * k) * 128] + pf.y * vp[(2 * k + 1) * 128];
    }
    float p64 = __half2float(prow[64]);
    sv  += p64 * vrow[64];
    sve += p64 * vp[64 * 128];
    int c2 = g * 16 + c;
    int o0 = 2 * c2;
    float val = og[o0] * RSBN * sv + ob[o0] + og[o0 + 1] * RSBN * sve + ob[o0 + 1];
    y[(((size_t)n * 128 + c2) * 128 + i) * 128 + w] = val;
  }
}

// ---------- G: shift-concat + instance-norm stats -> xo, per-(n,c) scale/shift ----------
__global__ void k_shift_stats(const float* __restrict__ y, const float* __restrict__ inw,
                              const float* __restrict__ inb, float* __restrict__ xo,
                              float* __restrict__ ss) {
  int nc = blockIdx.x;  // 256
  int n = nc >> 7, c = nc & 127;
  int t = threadIdx.x;
  const float* yn = y + (size_t)n * 128 * 16384;
  int sc_ch = c, dh = 0, dw = 0;
  if (c < 10)      { sc_ch = c;      dw = -2; }
  else if (c < 20) { sc_ch = c - 10; dw = 2; }
  else if (c < 30) { sc_ch = c - 20; dh = -2; }
  else if (c < 40) { sc_ch = c - 30; dh = 2; }
  const float* src = yn + (size_t)sc_ch * 16384;
  float* dst = xo + (size_t)nc * 16384;
  float s = 0.f, s2 = 0.f;
  for (int l = 0; l < 64; ++l) {
    int idx = t + l * 256;
    int h = idx >> 7, w = idx & 127;
    int hs = h + dh, ws_ = w + dw;
    float v = 0.f;
    if (hs >= 0 && hs < 128 && ws_ >= 0 && ws_ < 128) v = src[hs * 128 + ws_];
    dst[idx] = v;
    s += v; s2 += v * v;
  }
  __shared__ float rs[256], rs2[256];
  rs[t] = s; rs2[t] = s2;
  __syncthreads();
  for (int st = 128; st > 0; st >>= 1) {
    if (t < st) { rs[t] += rs[t + st]; rs2[t] += rs2[t + st]; }
    __syncthreads();
  }
  if (t == 0) {
    float mean = rs[0] * (1.0f / 16384.0f);
    float var = rs2[0] * (1.0f / 16384.0f) - mean * mean;
    float scale = inw[c] * rsqrtf(var + 1e-5f);
    ss[2 * nc] = scale;
    ss[2 * nc + 1] = inb[c] - mean * scale;
  }
}

// ---------- H1: h1 = gelu(W1 . xn), norm applied on load ----------
__global__ void k_mlp1(const float* __restrict__ xo, const float* __restrict__ ss,
                       const float* __restrict__ w1, float* __restrict__ h1) {
  const int pb = blockIdx.x * 128;
  const int ob = blockIdx.y * 64;
  const int n = blockIdx.z;
  __shared__ float wsm[64 * 16];
  __shared__ float xs[16 * 128];
  const int t = threadIdx.x;
  const int tx = t & 31, ty = t >> 5;
  float acc[8][4] = {};
  const float* xn_ = xo + (size_t)n * 128 * 16384;
  for (int k0 = 0; k0 < 128; k0 += 16) {
    #pragma unroll
    for (int l = 0; l < 4; ++l) {
      int idx = t + l * 256;
      wsm[idx] = w1[(ob + (idx >> 4)) * 128 + k0 + (idx & 15)];
    }
    #pragma unroll
    for (int l = 0; l < 8; ++l) {
      int idx = t + l * 256;
      int kk = idx >> 7, pp = idx & 127;
      int ch = k0 + kk;
      float sc = ss[2 * (n * 128 + ch)];
      float sh = ss[2 * (n * 128 + ch) + 1];
      xs[idx] = xn_[(size_t)ch * 16384 + pb + pp] * sc + sh;
    }
    __syncthreads();
    #pragma unroll
    for (int kk = 0; kk < 16; ++kk) {
      float4 xv = *(const float4*)&xs[kk * 128 + tx * 4];
      #pragma unroll
      for (int r = 0; r < 8; ++r) {
        float wv = wsm[(ty * 8 + r) * 16 + kk];
        acc[r][0] += wv * xv.x; acc[r][1] += wv * xv.y;
        acc[r][2] += wv * xv.z; acc[r][3] += wv * xv.w;
      }
    }
    __syncthreads();
  }
  #pragma unroll
  for (int r = 0; r < 8; ++r) {
    int o = ob + ty * 8 + r;
    float4 v;
    v.x = gelu_exact(acc[r][0]); v.y = gelu_exact(acc[r][1]);
    v.z = gelu_exact(acc[r][2]); v.w = gelu_exact(acc[r][3]);
    *(float4*)&h1[((size_t)(n * 512 + o)) * 16384 + pb + tx * 4] = v;
  }
}

// ---------- H2: out = W2 . h1 + identity(y) ----------
__global__ void k_mlp2(const float* __restrict__ h1, const float* __restrict__ w2,
                       const float* __restrict__ y, float* __restrict__ out) {
  const int pb = blockIdx.x * 128;
  const int ob = blockIdx.y * 64;
  const int n = blockIdx.z;
  __shared__ float wsm[64 * 16];
  __shared__ float xs[16 * 128];
  const int t = threadIdx.x;
  const int tx = t & 31, ty = t >> 5;
  float acc[8][4] = {};
  const float* hn = h1 + (size_t)n * 512 * 16384;
  for (int k0 = 0; k0 < 512; k0 += 16) {
    #pragma unroll
    for (int l = 0; l < 4; ++l) {
      int idx = t + l * 256;
      wsm[idx] = w2[(ob + (idx >> 4)) * 512 + k0 + (idx & 15)];
    }
    #pragma unroll
    for (int l = 0; l < 8; ++l) {
      int idx = t + l * 256;
      int kk = idx >> 7, pp = idx & 127;
      xs[idx] = hn[(size_t)(k0 + kk) * 16384 + pb + pp];
    }
    __syncthreads();
    #pragma unroll
    for (int kk = 0; kk < 16; ++kk) {
      float4 xv = *(const float4*)&xs[kk * 128 + tx * 4];
      #pragma unroll
      for (int r = 0; r < 8; ++r) {
        float wv = wsm[(ty * 8 + r) * 16 + kk];
        acc[r][0] += wv * xv.x; acc[r][1] += wv * xv.y;
        acc[r][2] += wv * xv.z; acc[r][3] += wv * xv.w;
      }
    }
    __syncthreads();
  }
  #pragma unroll
  for (int r = 0; r < 8; ++r) {
    int o = ob + ty * 8 + r;
    size_t base = ((size_t)(n * 128 + o)) * 16384 + pb + tx * 4;
    float4 yv = *(const float4*)&y[base];
    float4 v;
    v.x = acc[r][0] + yv.x; v.y = acc[r][1] + yv.y;
    v.z = acc[r][2] + yv.z; v.w = acc[r][3] + yv.w;
    *(float4*)&out[base] = v;
  }
}

extern "C" void kernel_launch(void* const* d_in, const int* in_sizes, int n_in,
                              void* d_out, int out_size, void* d_ws, size_t ws_size,
                              hipStream_t stream) {
  const float* x        = (const float*)d_in[0];
  const float* w_qkv    = (const float*)d_in[1];
  const float* bn_qkv_g = (const float*)d_in[2];
  const float* bn_qkv_b = (const float*)d_in[3];
  const float* bn_sim_g = (const float*)d_in[4];
  const float* bn_sim_b = (const float*)d_in[5];
  const float* bn_out_g = (const float*)d_in[6];
  const float* bn_out_b = (const float*)d_in[7];
  const float* in_w     = (const float*)d_in[8];
  const float* in_b     = (const float*)d_in[9];
  const float* mlp_w1   = (const float*)d_in[10];
  const float* mlp_w2   = (const float*)d_in[11];
  const float* base_rel = (const float*)d_in[12];
  float* Wp = (float*)d_ws;

  float* relA  = Wp + 0;          // 135,200 (pad 135,424)
  float* veI   = Wp + 135424;     // 133,120 (pad 133,376)
  float* qa    = Wp + 268800;     // 1,064,960
  float* ka    = Wp + 1333760;    // 1,064,960
  float* va    = Wp + 2398720;    // 2,129,920
  float* yb    = Wp + 4528640;    // 4,194,304
  float* ssb   = Wp + 8722944;    // 1,024
  float* xo    = Wp + 8723968;    // 4,194,304
  float* qkv   = Wp + 12918272;   // 8,388,608 (dead after k_down)
  float* simA  = Wp + 12918272;   // 8,652,800 (overlays qkv; dead after k_attn)
  float* h1    = Wp + 12918272;   // 16,777,216 (overlays simA)
  // peak: 29,695,488 floats = 118.8 MB (was 136.1 MB)

  k_relA<<<dim3(529), dim3(256), 0, stream>>>(base_rel, relA);
  k_vei<<<dim3(520), dim3(256), 0, stream>>>(relA, veI);
  k_qkv<<<dim3(128, 4, 2), dim3(256), 0, stream>>>(x, w_qkv, bn_qkv_g, bn_qkv_b, qkv);
  k_down<<<dim3(16640), dim3(256), 0, stream>>>(qkv, qa, ka, va);
  k_sim<<<dim3(2048), dim3(256), 0, stream>>>(qa, ka, relA, bn_sim_g, bn_sim_b, simA);
  k_attn<<<dim3(2048), dim3(256), 0, stream>>>(simA, va, veI, bn_out_g, bn_out_b, yb);
  k_shift_stats<<<dim3(256), dim3(256), 0, stream>>>(yb, in_w, in_b, xo, ssb);
  k_mlp1<<<dim3(128, 8, 2), dim3(256), 0, stream>>>(xo, ssb, mlp_w1, h1);
  k_mlp2<<<dim3(128, 2, 2), dim3(256), 0, stream>>>(h1, mlp_w2, yb, (float*)d_out);
}

// Round 3
// 334.469 us; speedup vs baseline: 2.1858x; 1.5421x over previous
//
#include <hip/hip_runtime.h>
#include <hip/hip_bf16.h>
#include <hip/hip_fp16.h>

// Problem constants
#define GG 8
#define GPP 16
#define AA 65
#define HH 128
#define CC 128
#define NN 2
#define WW 128
#define BB 256            // N*W
#define EDC_ 10
#define OFF_ 2

__device__ __forceinline__ void rz_taps(int o, float scale, int in_size,
                                        int& ia, int& ib, float& f) {
  // jax.image.resize 'linear' antialias=False == clamped-index lerp.
  float pos = (o + 0.5f) * scale - 0.5f;
  float fl = floorf(pos);
  int i0 = (int)fl;
  f = pos - fl;
  ia = i0 < 0 ? 0 : i0;
  int i1 = i0 + 1;
  ib = i1 > (in_size - 1) ? (in_size - 1) : i1;
}

// Compile-time 128->65 tap: pos = (j+0.5)*65/128-0.5 = (130j-63)/256 exactly.
#define JTAP(jc, ja, jb, fj) \
  const int num_ = 130 * (jc) - 63;               \
  const int fl_ = num_ >> 8;                      \
  const int ja = fl_ < 0 ? 0 : fl_;               \
  const int jb = (fl_ + 1 > 64) ? 64 : (fl_ + 1); \
  const float fj = (float)(num_ - (fl_ << 8)) * 0.00390625f;

__device__ __forceinline__ float gelu_exact(float v) {
  return 0.5f * v * (1.0f + erff(v * 0.70710678118654752f));
}

#define RSBN 0.99999500003749977f  // 1/sqrt(1+1e-5)

// ---------- A: base_relative (32,255,255) -> relA (32,65,65); also emit
// relAT[c][i][j] = relA[8+c][j][i] (transposed k_emb) for coalesced kr ----------
__global__ void k_relA(const float* __restrict__ base, float* __restrict__ relA,
                       float* __restrict__ relAT) {
  int idx = blockIdx.x * 256 + threadIdx.x;
  if (idx >= 32 * AA * AA) return;
  int j = idx % AA;
  int r = idx / AA;
  int i = r % AA;
  int c = r / AA;
  int ia, ib, ja, jb; float fi, fj;
  rz_taps(i, 255.0f / 65.0f, 255, ia, ib, fi);
  rz_taps(j, 255.0f / 65.0f, 255, ja, jb, fj);
  const float* S = base + (size_t)c * 255 * 255;
  float v = (1.0f - fi) * ((1.0f - fj) * S[ia * 255 + ja] + fj * S[ia * 255 + jb])
          + fi * ((1.0f - fj) * S[ib * 255 + ja] + fj * S[ib * 255 + jb]);
  relA[idx] = v;
  if (c >= 8 && c < 16) relAT[(c - 8) * (AA * AA) + j * AA + i] = v;
}

// ---------- B: veI[c][a][i] = i-upsampled (65->128) v_emb on the 65-j grid ----------
__global__ void k_vei(const float* __restrict__ relA, float* __restrict__ veI) {
  int idx = blockIdx.x * 256 + threadIdx.x;  // 16*65*128 = 133,120
  if (idx >= 16 * AA * 128) return;
  int i = idx & 127;
  int r = idx >> 7;           // c*65 + a
  int a = r % AA, c = r / AA;
  int ia, ib; float fi;
  rz_taps(i, 65.0f / 128.0f, 65, ia, ib, fi);
  const float* S = relA + (size_t)(16 + c) * (AA * AA);
  veI[idx] = (1.0f - fi) * S[ia * AA + a] + fi * S[ib * AA + a];
}

// ---------- C: qkv GEMM + BN ----------
__global__ void k_qkv(const float* __restrict__ x, const float* __restrict__ wq,
                      const float* __restrict__ bg, const float* __restrict__ bb,
                      float* __restrict__ out) {
  const int pb = blockIdx.x * 128;
  const int ob = blockIdx.y * 64;
  const int n = blockIdx.z;
  __shared__ float wsm[64 * 16];
  __shared__ float xs[16 * 128];
  const int t = threadIdx.x;
  const int tx = t & 31, ty = t >> 5;
  float acc[8][4] = {};
  const float* xn_ = x + (size_t)n * CC * 16384;
  for (int k0 = 0; k0 < 128; k0 += 16) {
    #pragma unroll
    for (int l = 0; l < 4; ++l) {
      int idx = t + l * 256;
      wsm[idx] = wq[(ob + (idx >> 4)) * 128 + k0 + (idx & 15)];
    }
    #pragma unroll
    for (int l = 0; l < 8; ++l) {
      int idx = t + l * 256;
      int kk = idx >> 7, pp = idx & 127;
      xs[idx] = xn_[(size_t)(k0 + kk) * 16384 + pb + pp];
    }
    __syncthreads();
    #pragma unroll
    for (int kk = 0; kk < 16; ++kk) {
      float4 xv = *(const float4*)&xs[kk * 128 + tx * 4];
      #pragma unroll
      for (int r = 0; r < 8; ++r) {
        float wv = wsm[(ty * 8 + r) * 16 + kk];
        acc[r][0] += wv * xv.x; acc[r][1] += wv * xv.y;
        acc[r][2] += wv * xv.z; acc[r][3] += wv * xv.w;
      }
    }
    __syncthreads();
  }
  #pragma unroll
  for (int r = 0; r < 8; ++r) {
    int o = ob + ty * 8 + r;
    float sc = bg[o] * RSBN, sh = bb[o];
    float4 v;
    v.x = acc[r][0] * sc + sh; v.y = acc[r][1] * sc + sh;
    v.z = acc[r][2] * sc + sh; v.w = acc[r][3] * sc + sh;
    *(float4*)&out[((size_t)(n * 256 + o)) * 16384 + pb + tx * 4] = v;
  }
}

// ---------- D: downsample qkv along i (128->65), split. w-fastest => coalesced reads ----------
__global__ void k_down(const float* __restrict__ qkv, float* __restrict__ qa,
                       float* __restrict__ ka, float* __restrict__ va) {
  int idx = blockIdx.x * 256 + threadIdx.x;  // 128w*65a*32cc*8g*2n = 4,259,840
  if (idx >= BB * GG * 32 * AA) return;
  int w = idx & 127;
  int r = idx >> 7;
  int a = r % AA; r /= AA;
  int cc = r & 31; r >>= 5;
  int g = r & 7;
  int n = r >> 3;
  int o = g * 32 + cc;
  int ia, ib; float f;
  rz_taps(a, 128.0f / 65.0f, 128, ia, ib, f);
  const float* src = qkv + ((size_t)(n * 256 + o)) * 16384 + w;
  float v = (1.0f - f) * src[ia * 128] + f * src[ib * 128];
  int bg = (n * 128 + w) * 8 + g;
  if (cc < 8)       qa[((size_t)bg * 8 + cc) * AA + a] = v;
  else if (cc < 16) ka[((size_t)bg * 8 + (cc - 8)) * AA + a] = v;
  else              va[((size_t)bg * 16 + (cc - 16)) * AA + a] = v;
}

// ---------- F: fused sim(qk+qr+kr+BN) + softmax(65->128 fold) + sv/sve + bn_out ----------
__global__ void k_attn(const float* __restrict__ qa, const float* __restrict__ ka,
                       const float* __restrict__ va, const float* __restrict__ relA,
                       const float* __restrict__ relAT, const float* __restrict__ veI,
                       const float* __restrict__ sg, const float* __restrict__ sb,
                       const float* __restrict__ og, const float* __restrict__ ob,
                       float* __restrict__ y) {
  int bg = blockIdx.x;
  int b = bg >> 3, g = bg & 7;
  int n = b >> 7, w = b & 127;
  __shared__ float Ss[AA * AA];         // 16,900 B
  __shared__ __half Pws[128 * 66];      // 16,896 B
  __shared__ float u0[1040];            // 4,160 B: qs|ks during sim, vas after
  float* qs = u0;
  float* ks = u0 + 520;
  float* vas = u0;
  int t = threadIdx.x;

  // phase 1: stage q,k rows
  for (int l = t; l < 1040; l += 256) u0[l] = (l < 520) ? qa[(size_t)bg * 520 + l]
                                                        : ka[(size_t)bg * 520 + (l - 520)];
  __syncthreads();

  // phase 2: sim 65x65 (BN-combined qk+qr+kr)
  {
    float sqk = sg[g] * RSBN, sqr = sg[8 + g] * RSBN, skr = sg[16 + g] * RSBN;
    float badd = sb[g] + sb[8 + g] + sb[16 + g];
    for (int l = t; l < AA * AA; l += 256) {
      int i = l / AA, j = l - i * AA;
      float qk = 0.f, qr = 0.f, kr = 0.f;
      #pragma unroll
      for (int c = 0; c < 8; ++c) {
        float qv = qs[c * AA + i], kv = ks[c * AA + j];
        qk += qv * kv;
        qr += qv * relA[c * (AA * AA) + l];
        kr += kv * relAT[c * (AA * AA) + l];
      }
      Ss[l] = sqk * qk + sqr * qr + skr * kr + badd;
    }
  }
  __syncthreads();

  // phase 3: vas load (overlays qs/ks) + softmax folded to 65 taps, in registers
  for (int l = t; l < 16 * AA; l += 256) vas[l] = va[(size_t)bg * (16 * AA) + l];
  {
    const int i = t >> 1, h = t & 1;
    int ia, ib; float fi;
    rz_taps(i, 65.0f / 128.0f, 65, ia, ib, fi);
    const float* r0 = Ss + ia * AA;
    const float* r1 = Ss + ib * AA;
    const float wi0 = 1.0f - fi;
    float mx = -1e30f;
    if (h == 0) {
      #pragma unroll
      for (int j = 0; j < 64; ++j) {
        JTAP(j, ja, jb, fj);
        float v = wi0 * ((1.0f - fj) * r0[ja] + fj * r0[jb])
                + fi * ((1.0f - fj) * r1[ja] + fj * r1[jb]);
        mx = fmaxf(mx, v);
      }
    } else {
      #pragma unroll
      for (int j = 64; j < 128; ++j) {
        JTAP(j, ja, jb, fj);
        float v = wi0 * ((1.0f - fj) * r0[ja] + fj * r0[jb])
                + fi * ((1.0f - fj) * r1[ja] + fj * r1[jb]);
        mx = fmaxf(mx, v);
      }
    }
    mx = fmaxf(mx, __shfl_xor(mx, 1));
    float p[33];
    #pragma unroll
    for (int k = 0; k < 33; ++k) p[k] = 0.f;
    float sum = 0.f;
    if (h == 0) {
      #pragma unroll
      for (int j = 0; j < 64; ++j) {
        JTAP(j, ja, jb, fj);
        float v = wi0 * ((1.0f - fj) * r0[ja] + fj * r0[jb])
                + fi * ((1.0f - fj) * r1[ja] + fj * r1[jb]);
        float e = __expf(v - mx);
        sum += e;
        p[ja] += e * (1.0f - fj);
        p[jb] += e * fj;
      }
    } else {
      #pragma unroll
      for (int j = 64; j < 128; ++j) {
        JTAP(j, ja, jb, fj);
        float v = wi0 * ((1.0f - fj) * r0[ja] + fj * r0[jb])
                + fi * ((1.0f - fj) * r1[ja] + fj * r1[jb]);
        float e = __expf(v - mx);
        sum += e;
        p[ja - 32] += e * (1.0f - fj);
        p[jb - 32] += e * fj;
      }
    }
    sum += __shfl_xor(sum, 1);
    float other = __shfl_xor(h ? p[0] : p[32], 1);
    float inv = 1.0f / sum;
    __half* prow = &Pws[i * 66];
    if (h == 0) {
      p[32] += other;
      #pragma unroll
      for (int k = 0; k < 33; ++k) prow[k] = __float2half(p[k] * inv);
    } else {
      #pragma unroll
      for (int k = 1; k < 33; ++k) prow[32 + k] = __float2half(p[k] * inv);
    }
  }
  __syncthreads();

  // phase 4: sv/sve contraction over 65 taps + bn_out + pair-sum -> y
  #pragma unroll
  for (int l = 0; l < 8; ++l) {
    int oi = t + l * 256;          // 0..2047
    int c = oi >> 7, i = oi & 127;
    const __half* prow = &Pws[i * 66];
    const float* vrow = &vas[c * AA];
    const float* vp = veI + (size_t)c * (AA * 128) + i;
    float sv = 0.f, sve = 0.f;
    #pragma unroll 8
    for (int k = 0; k < 32; ++k) {
      __half2 ph = *(const __half2*)(prow + 2 * k);
      float2 pf = __half22float2(ph);
      sv  += pf.x * vrow[2 * k]       + pf.y * vrow[2 * k + 1];
      sve += pf.x * vp[(2 * k) * 128] + pf.y * vp[(2 * k + 1) * 128];
    }
    float p64 = __half2float(prow[64]);
    sv  += p64 * vrow[64];
    sve += p64 * vp[64 * 128];
    int c2 = g * 16 + c;
    int o0 = 2 * c2;
    float val = og[o0] * RSBN * sv + ob[o0] + og[o0 + 1] * RSBN * sve + ob[o0 + 1];
    y[(((size_t)n * 128 + c2) * 128 + i) * 128 + w] = val;
  }
}

// ---------- G: shift-concat + instance-norm stats ----------
__global__ void k_shift_stats(const float* __restrict__ y, const float* __restrict__ inw,
                              const float* __restrict__ inb, float* __restrict__ xo,
                              float* __restrict__ ss) {
  int nc = blockIdx.x;  // 256
  int n = nc >> 7, c = nc & 127;
  int t = threadIdx.x;
  const float* yn = y + (size_t)n * 128 * 16384;
  int sc_ch = c, dh = 0, dw = 0;
  if (c < 10)      { sc_ch = c;      dw = -2; }
  else if (c < 20) { sc_ch = c - 10; dw = 2; }
  else if (c < 30) { sc_ch = c - 20; dh = -2; }
  else if (c < 40) { sc_ch = c - 30; dh = 2; }
  const float* src = yn + (size_t)sc_ch * 16384;
  float* dst = xo + (size_t)nc * 16384;
  float s = 0.f, s2 = 0.f;
  for (int l = 0; l < 64; ++l) {
    int idx = t + l * 256;
    int h = idx >> 7, w = idx & 127;
    int hs = h + dh, ws_ = w + dw;
    float v = 0.f;
    if (hs >= 0 && hs < 128 && ws_ >= 0 && ws_ < 128) v = src[hs * 128 + ws_];
    dst[idx] = v;
    s += v; s2 += v * v;
  }
  __shared__ float rs[256], rs2[256];
  rs[t] = s; rs2[t] = s2;
  __syncthreads();
  for (int st = 128; st > 0; st >>= 1) {
    if (t < st) { rs[t] += rs[t + st]; rs2[t] += rs2[t + st]; }
    __syncthreads();
  }
  if (t == 0) {
    float mean = rs[0] * (1.0f / 16384.0f);
    float var = rs2[0] * (1.0f / 16384.0f) - mean * mean;
    float scale = inw[c] * rsqrtf(var + 1e-5f);
    ss[2 * nc] = scale;
    ss[2 * nc + 1] = inb[c] - mean * scale;
  }
}

// ---------- H1: h1 = gelu(W1 . xn) ----------
__global__ void k_mlp1(const float* __restrict__ xo, const float* __restrict__ ss,
                       const float* __restrict__ w1, float* __restrict__ h1) {
  const int pb = blockIdx.x * 128;
  const int ob = blockIdx.y * 64;
  const int n = blockIdx.z;
  __shared__ float wsm[64 * 16];
  __shared__ float xs[16 * 128];
  const int t = threadIdx.x;
  const int tx = t & 31, ty = t >> 5;
  float acc[8][4] = {};
  const float* xn_ = xo + (size_t)n * 128 * 16384;
  for (int k0 = 0; k0 < 128; k0 += 16) {
    #pragma unroll
    for (int l = 0; l < 4; ++l) {
      int idx = t + l * 256;
      wsm[idx] = w1[(ob + (idx >> 4)) * 128 + k0 + (idx & 15)];
    }
    #pragma unroll
    for (int l = 0; l < 8; ++l) {
      int idx = t + l * 256;
      int kk = idx >> 7, pp = idx & 127;
      int ch = k0 + kk;
      float sc = ss[2 * (n * 128 + ch)];
      float sh = ss[2 * (n * 128 + ch) + 1];
      xs[idx] = xn_[(size_t)ch * 16384 + pb + pp] * sc + sh;
    }
    __syncthreads();
    #pragma unroll
    for (int kk = 0; kk < 16; ++kk) {
      float4 xv = *(const float4*)&xs[kk * 128 + tx * 4];
      #pragma unroll
      for (int r = 0; r < 8; ++r) {
        float wv = wsm[(ty * 8 + r) * 16 + kk];
        acc[r][0] += wv * xv.x; acc[r][1] += wv * xv.y;
        acc[r][2] += wv * xv.z; acc[r][3] += wv * xv.w;
      }
    }
    __syncthreads();
  }
  #pragma unroll
  for (int r = 0; r < 8; ++r) {
    int o = ob + ty * 8 + r;
    float4 v;
    v.x = gelu_exact(acc[r][0]); v.y = gelu_exact(acc[r][1]);
    v.z = gelu_exact(acc[r][2]); v.w = gelu_exact(acc[r][3]);
    *(float4*)&h1[((size_t)(n * 512 + o)) * 16384 + pb + tx * 4] = v;
  }
}

// ---------- H2: out = W2 . h1 + identity(y) ----------
__global__ void k_mlp2(const float* __restrict__ h1, const float* __restrict__ w2,
                       const float* __restrict__ y, float* __restrict__ out) {
  const int pb = blockIdx.x * 128;
  const int ob = blockIdx.y * 64;
  const int n = blockIdx.z;
  __shared__ float wsm[64 * 16];
  __shared__ float xs[16 * 128];
  const int t = threadIdx.x;
  const int tx = t & 31, ty = t >> 5;
  float acc[8][4] = {};
  const float* hn = h1 + (size_t)n * 512 * 16384;
  for (int k0 = 0; k0 < 512; k0 += 16) {
    #pragma unroll
    for (int l = 0; l < 4; ++l) {
      int idx = t + l * 256;
      wsm[idx] = w2[(ob + (idx >> 4)) * 512 + k0 + (idx & 15)];
    }
    #pragma unroll
    for (int l = 0; l < 8; ++l) {
      int idx = t + l * 256;
      int kk = idx >> 7, pp = idx & 127;
      xs[idx] = hn[(size_t)(k0 + kk) * 16384 + pb + pp];
    }
    __syncthreads();
    #pragma unroll
    for (int kk = 0; kk < 16; ++kk) {
      float4 xv = *(const float4*)&xs[kk * 128 + tx * 4];
      #pragma unroll
      for (int r = 0; r < 8; ++r) {
        float wv = wsm[(ty * 8 + r) * 16 + kk];
        acc[r][0] += wv * xv.x; acc[r][1] += wv * xv.y;
        acc[r][2] += wv * xv.z; acc[r][3] += wv * xv.w;
      }
    }
    __syncthreads();
  }
  #pragma unroll
  for (int r = 0; r < 8; ++r) {
    int o = ob + ty * 8 + r;
    size_t base = ((size_t)(n * 128 + o)) * 16384 + pb + tx * 4;
    float4 yv = *(const float4*)&y[base];
    float4 v;
    v.x = acc[r][0] + yv.x; v.y = acc[r][1] + yv.y;
    v.z = acc[r][2] + yv.z; v.w = acc[r][3] + yv.w;
    *(float4*)&out[base] = v;
  }
}

extern "C" void kernel_launch(void* const* d_in, const int* in_sizes, int n_in,
                              void* d_out, int out_size, void* d_ws, size_t ws_size,
                              hipStream_t stream) {
  const float* x        = (const float*)d_in[0];
  const float* w_qkv    = (const float*)d_in[1];
  const float* bn_qkv_g = (const float*)d_in[2];
  const float* bn_qkv_b = (const float*)d_in[3];
  const float* bn_sim_g = (const float*)d_in[4];
  const float* bn_sim_b = (const float*)d_in[5];
  const float* bn_out_g = (const float*)d_in[6];
  const float* bn_out_b = (const float*)d_in[7];
  const float* in_w     = (const float*)d_in[8];
  const float* in_b     = (const float*)d_in[9];
  const float* mlp_w1   = (const float*)d_in[10];
  const float* mlp_w2   = (const float*)d_in[11];
  const float* base_rel = (const float*)d_in[12];
  float* Wp = (float*)d_ws;

  float* relA  = Wp + 0;          // 135,200 (pad 135,424)
  float* relAT = Wp + 135424;     // 33,800 (pad 33,920)
  float* veI   = Wp + 169344;     // 133,120 (pad 133,376)
  float* qa    = Wp + 302720;     // 1,064,960
  float* ka    = Wp + 1367680;    // 1,064,960
  float* va    = Wp + 2432640;    // 2,129,920
  float* yb    = Wp + 4562560;    // 4,194,304
  float* ssb   = Wp + 8756864;    // 1,024
  float* xo    = Wp + 8757888;    // 4,194,304
  float* qkv   = Wp + 12952192;   // 8,388,608 (dead after k_down)
  float* h1    = Wp + 12952192;   // 16,777,216 (overlays qkv)
  // peak: 29,729,408 floats = 118.9 MB

  k_relA<<<dim3(529), dim3(256), 0, stream>>>(base_rel, relA, relAT);
  k_vei<<<dim3(520), dim3(256), 0, stream>>>(relA, veI);
  k_qkv<<<dim3(128, 4, 2), dim3(256), 0, stream>>>(x, w_qkv, bn_qkv_g, bn_qkv_b, qkv);
  k_down<<<dim3(16640), dim3(256), 0, stream>>>(qkv, qa, ka, va);
  k_attn<<<dim3(2048), dim3(256), 0, stream>>>(qa, ka, va, relA, relAT, veI,
                                               bn_sim_g, bn_sim_b, bn_out_g, bn_out_b, yb);
  k_shift_stats<<<dim3(256), dim3(256), 0, stream>>>(yb, in_w, in_b, xo, ssb);
  k_mlp1<<<dim3(128, 8, 2), dim3(256), 0, stream>>>(xo, ssb, mlp_w1, h1);
  k_mlp2<<<dim3(128, 2, 2), dim3(256), 0, stream>>>(h1, mlp_w2, yb, (float*)d_out);
}

// Round 4
// 260.905 us; speedup vs baseline: 2.8022x; 1.2820x over previous
//
#include <hip/hip_runtime.h>
#include <hip/hip_bf16.h>
#include <hip/hip_fp16.h>

#define GG 8
#define GPP 16
#define AA 65
#define HH 128
#define CC 128
#define NN 2
#define WW 128
#define BB 256
#define EDC_ 10
#define OFF_ 2

typedef __attribute__((ext_vector_type(8))) short bf16x8;
typedef __attribute__((ext_vector_type(4))) float f32x4;
#define MFMA16(a, b, c) __builtin_amdgcn_mfma_f32_16x16x32_bf16(a, b, c, 0, 0, 0)

__device__ __forceinline__ void rz_taps(int o, float scale, int in_size,
                                        int& ia, int& ib, float& f) {
  float pos = (o + 0.5f) * scale - 0.5f;
  float fl = floorf(pos);
  int i0 = (int)fl;
  f = pos - fl;
  ia = i0 < 0 ? 0 : i0;
  int i1 = i0 + 1;
  ib = i1 > (in_size - 1) ? (in_size - 1) : i1;
}

// Compile-time 128->65 tap: pos = (j+0.5)*65/128-0.5 = (130j-63)/256 exactly.
#define JTAP(jc, ja, jb, fj) \
  const int num_ = 130 * (jc) - 63;               \
  const int fl_ = num_ >> 8;                      \
  const int ja = fl_ < 0 ? 0 : fl_;               \
  const int jb = (fl_ + 1 > 64) ? 64 : (fl_ + 1); \
  const float fj = (float)(num_ - (fl_ << 8)) * 0.00390625f;

__device__ __forceinline__ float gelu_exact(float v) {
  return 0.5f * v * (1.0f + erff(v * 0.70710678118654752f));
}

__device__ __forceinline__ short f2b(float f) {
  __hip_bfloat16 h = __float2bfloat16(f);
  return *reinterpret_cast<short*>(&h);
}

#define RSBN 0.99999500003749977f  // 1/sqrt(1+1e-5)

// ---------- W: pre-convert weights to bf16 ----------
__global__ void k_wbf(const float* __restrict__ wq, const float* __restrict__ w1,
                      const float* __restrict__ w2, short* __restrict__ wqb,
                      short* __restrict__ w1b, short* __restrict__ w2b) {
  int i = blockIdx.x * 256 + threadIdx.x;
  if (i < 32768) wqb[i] = f2b(wq[i]);
  if (i < 65536) { w1b[i] = f2b(w1[i]); w2b[i] = f2b(w2[i]); }
}

// ---------- A: base_relative (32,255,255) -> relA (32,65,65) + padded q/k copies ----------
__global__ void k_relA(const float* __restrict__ base, float* __restrict__ relA,
                       float* __restrict__ relAp, float* __restrict__ relATp) {
  int idx = blockIdx.x * 256 + threadIdx.x;
  if (idx >= 32 * AA * AA) return;
  int j = idx % AA;
  int r = idx / AA;
  int i = r % AA;
  int c = r / AA;
  int ia, ib, ja, jb; float fi, fj;
  rz_taps(i, 255.0f / 65.0f, 255, ia, ib, fi);
  rz_taps(j, 255.0f / 65.0f, 255, ja, jb, fj);
  const float* S = base + (size_t)c * 255 * 255;
  float v = (1.0f - fi) * ((1.0f - fj) * S[ia * 255 + ja] + fj * S[ia * 255 + jb])
          + fi * ((1.0f - fj) * S[ib * 255 + ja] + fj * S[ib * 255 + jb]);
  relA[idx] = v;
  if (c < 8) relAp[c * 4420 + i * 68 + j] = v;                 // q_emb padded
  else if (c < 16) relATp[(c - 8) * 4420 + j * 68 + i] = v;    // k_emb transposed padded
}

// ---------- B: veI[c][a][i] = i-upsampled (65->128) v_emb on the 65-j grid ----------
__global__ void k_vei(const float* __restrict__ relA, float* __restrict__ veI) {
  int idx = blockIdx.x * 256 + threadIdx.x;  // 16*65*128
  if (idx >= 16 * AA * 128) return;
  int i = idx & 127;
  int r = idx >> 7;
  int a = r % AA, c = r / AA;
  int ia, ib; float fi;
  rz_taps(i, 65.0f / 128.0f, 65, ia, ib, fi);
  const float* S = relA + (size_t)(16 + c) * (AA * AA);
  veI[idx] = (1.0f - fi) * S[ia * AA + a] + fi * S[ib * AA + a];
}

// ---------- MFMA GEMM 1: qkv = BN(Wqkv . x) ----------
__global__ __launch_bounds__(256) void k_qkv_mfma(
    const float* __restrict__ x, const short* __restrict__ wqb,
    const float* __restrict__ bg, const float* __restrict__ bb,
    float* __restrict__ out) {
  const int pb = blockIdx.x * 128;
  const int ob = blockIdx.y * 128;
  const int n = blockIdx.z;
  __shared__ short Asm[128 * 40];
  __shared__ short Bsm[128 * 40];
  const int t = threadIdx.x;
  const int lane = t & 63, wv = t >> 6;
  const int wm = wv >> 1, wn = wv & 1;
  const int lr = lane & 15, lk = (lane >> 4) * 8;
  f32x4 acc[4][4];
  #pragma unroll
  for (int a = 0; a < 4; ++a)
    #pragma unroll
    for (int b = 0; b < 4; ++b)
      #pragma unroll
      for (int q = 0; q < 4; ++q) acc[a][b][q] = 0.f;
  const float* X = x + (size_t)n * 128 * 16384;
  for (int k0 = 0; k0 < 128; k0 += 32) {
    #pragma unroll
    for (int i2 = 0; i2 < 2; ++i2) {
      int u = t + 256 * i2;
      int row = u >> 2, kq = (u & 3) * 8;
      *(bf16x8*)&Asm[row * 40 + kq] = *(const bf16x8*)&wqb[(ob + row) * 128 + k0 + kq];
    }
    #pragma unroll
    for (int i4 = 0; i4 < 4; ++i4) {
      int u = t + 256 * i4;
      int k = u >> 5, p4 = (u & 31) * 4;
      float4 xv = *(const float4*)&X[(size_t)(k0 + k) * 16384 + pb + p4];
      Bsm[(p4 + 0) * 40 + k] = f2b(xv.x);
      Bsm[(p4 + 1) * 40 + k] = f2b(xv.y);
      Bsm[(p4 + 2) * 40 + k] = f2b(xv.z);
      Bsm[(p4 + 3) * 40 + k] = f2b(xv.w);
    }
    __syncthreads();
    bf16x8 af[4], bfr[4];
    #pragma unroll
    for (int mf = 0; mf < 4; ++mf) af[mf] = *(bf16x8*)&Asm[(wm * 64 + mf * 16 + lr) * 40 + lk];
    #pragma unroll
    for (int nf = 0; nf < 4; ++nf) bfr[nf] = *(bf16x8*)&Bsm[(wn * 64 + nf * 16 + lr) * 40 + lk];
    #pragma unroll
    for (int mf = 0; mf < 4; ++mf)
      #pragma unroll
      for (int nf = 0; nf < 4; ++nf)
        acc[mf][nf] = MFMA16(af[mf], bfr[nf], acc[mf][nf]);
    __syncthreads();
  }
  #pragma unroll
  for (int mf = 0; mf < 4; ++mf) {
    #pragma unroll
    for (int r = 0; r < 4; ++r) {
      int o = ob + wm * 64 + mf * 16 + (lane >> 4) * 4 + r;
      float sc = bg[o] * RSBN, sh = bb[o];
      #pragma unroll
      for (int nf = 0; nf < 4; ++nf) {
        int p = pb + wn * 64 + nf * 16 + lr;
        out[((size_t)(n * 256 + o)) * 16384 + p] = acc[mf][nf][r] * sc + sh;
      }
    }
  }
}

// ---------- D: downsample qkv along i (128->65), split ----------
__global__ void k_down(const float* __restrict__ qkv, float* __restrict__ qa,
                       float* __restrict__ ka, float* __restrict__ va) {
  int idx = blockIdx.x * 256 + threadIdx.x;
  if (idx >= BB * GG * 32 * AA) return;
  int w = idx & 127;
  int r = idx >> 7;
  int a = r % AA; r /= AA;
  int cc = r & 31; r >>= 5;
  int g = r & 7;
  int n = r >> 3;
  int o = g * 32 + cc;
  int ia, ib; float f;
  rz_taps(a, 128.0f / 65.0f, 128, ia, ib, f);
  const float* src = qkv + ((size_t)(n * 256 + o)) * 16384 + w;
  float v = (1.0f - f) * src[ia * 128] + f * src[ib * 128];
  int bg = (n * 128 + w) * 8 + g;
  if (cc < 8)       qa[((size_t)bg * 8 + cc) * AA + a] = v;
  else if (cc < 16) ka[((size_t)bg * 8 + (cc - 8)) * AA + a] = v;
  else              va[((size_t)bg * 16 + (cc - 16)) * AA + a] = v;
}

// ---------- F: fused sim + softmax-fold + sv/sve + bn_out ----------
__global__ void k_attn(const float* __restrict__ qa, const float* __restrict__ ka,
                       const float* __restrict__ va, const float* __restrict__ relAp,
                       const float* __restrict__ relATp, const float* __restrict__ veI,
                       const float* __restrict__ sg, const float* __restrict__ sb,
                       const float* __restrict__ og, const float* __restrict__ ob,
                       float* __restrict__ y) {
  int bg = blockIdx.x;
  int b = bg >> 3, g = bg & 7;
  int n = b >> 7, w = b & 127;
  __shared__ float Ss[65 * 68];         // padded rows, 17,680 B
  __shared__ __half Pws[128 * 66];      // 16,896 B
  __shared__ float u0[1064];            // qs(520)|ksp(544) during sim, vas after
  float* qs = u0;
  float* ksp = u0 + 520;
  float* vas = u0;
  int t = threadIdx.x;

  for (int l = t; l < 520; l += 256) qs[l] = qa[(size_t)bg * 520 + l];
  for (int l = t; l < 520; l += 256) {
    int c = l / 65, j = l - c * 65;
    ksp[c * 68 + j] = ka[(size_t)bg * 520 + l];
  }
  __syncthreads();

  // phase 2: sim 65x65 vectorized over j-quads
  {
    float sqk = sg[g] * RSBN, sqr = sg[8 + g] * RSBN, skr = sg[16 + g] * RSBN;
    float badd = sb[g] + sb[8 + g] + sb[16 + g];
    for (int u = t; u < 65 * 17; u += 256) {
      int i = u / 17, jq = u - i * 17;
      float qv[8];
      #pragma unroll
      for (int c = 0; c < 8; ++c) qv[c] = qs[c * 65 + i];
      if (jq < 16) {
        int j0 = jq * 4;
        int lofs = i * 68 + j0;
        float qk0 = 0, qk1 = 0, qk2 = 0, qk3 = 0;
        float qr0 = 0, qr1 = 0, qr2 = 0, qr3 = 0;
        float kr0 = 0, kr1 = 0, kr2 = 0, kr3 = 0;
        #pragma unroll
        for (int c = 0; c < 8; ++c) {
          float4 kv = *(const float4*)&ksp[c * 68 + j0];
          float4 ra = *(const float4*)&relAp[c * 4420 + lofs];
          float4 rt = *(const float4*)&relATp[c * 4420 + lofs];
          float q = qv[c];
          qk0 += q * kv.x; qk1 += q * kv.y; qk2 += q * kv.z; qk3 += q * kv.w;
          qr0 += q * ra.x; qr1 += q * ra.y; qr2 += q * ra.z; qr3 += q * ra.w;
          kr0 += kv.x * rt.x; kr1 += kv.y * rt.y; kr2 += kv.z * rt.z; kr3 += kv.w * rt.w;
        }
        float4 res;
        res.x = sqk * qk0 + sqr * qr0 + skr * kr0 + badd;
        res.y = sqk * qk1 + sqr * qr1 + skr * kr1 + badd;
        res.z = sqk * qk2 + sqr * qr2 + skr * kr2 + badd;
        res.w = sqk * qk3 + sqr * qr3 + skr * kr3 + badd;
        *(float4*)&Ss[lofs] = res;
      } else {
        float qk = 0, qr = 0, kr = 0;
        int lofs = i * 68 + 64;
        #pragma unroll
        for (int c = 0; c < 8; ++c) {
          float kv = ksp[c * 68 + 64];
          qk += qv[c] * kv;
          qr += qv[c] * relAp[c * 4420 + lofs];
          kr += kv * relATp[c * 4420 + lofs];
        }
        Ss[lofs] = sqk * qk + sqr * qr + skr * kr + badd;
      }
    }
  }
  __syncthreads();

  // phase 3: vas load (overlays u0) + softmax folded to 65 taps in registers
  for (int l = t; l < 16 * AA; l += 256) vas[l] = va[(size_t)bg * (16 * AA) + l];
  {
    const int i = t >> 1, h = t & 1;
    int ia, ib; float fi;
    rz_taps(i, 65.0f / 128.0f, 65, ia, ib, fi);
    const float* r0 = Ss + ia * 68;
    const float* r1 = Ss + ib * 68;
    const float wi0 = 1.0f - fi;
    float mx = -1e30f;
    if (h == 0) {
      #pragma unroll
      for (int j = 0; j < 64; ++j) {
        JTAP(j, ja, jb, fj);
        float v = wi0 * ((1.0f - fj) * r0[ja] + fj * r0[jb])
                + fi * ((1.0f - fj) * r1[ja] + fj * r1[jb]);
        mx = fmaxf(mx, v);
      }
    } else {
      #pragma unroll
      for (int j = 64; j < 128; ++j) {
        JTAP(j, ja, jb, fj);
        float v = wi0 * ((1.0f - fj) * r0[ja] + fj * r0[jb])
                + fi * ((1.0f - fj) * r1[ja] + fj * r1[jb]);
        mx = fmaxf(mx, v);
      }
    }
    mx = fmaxf(mx, __shfl_xor(mx, 1));
    float p[33];
    #pragma unroll
    for (int k = 0; k < 33; ++k) p[k] = 0.f;
    float sum = 0.f;
    if (h == 0) {
      #pragma unroll
      for (int j = 0; j < 64; ++j) {
        JTAP(j, ja, jb, fj);
        float v = wi0 * ((1.0f - fj) * r0[ja] + fj * r0[jb])
                + fi * ((1.0f - fj) * r1[ja] + fj * r1[jb]);
        float e = __expf(v - mx);
        sum += e;
        p[ja] += e * (1.0f - fj);
        p[jb] += e * fj;
      }
    } else {
      #pragma unroll
      for (int j = 64; j < 128; ++j) {
        JTAP(j, ja, jb, fj);
        float v = wi0 * ((1.0f - fj) * r0[ja] + fj * r0[jb])
                + fi * ((1.0f - fj) * r1[ja] + fj * r1[jb]);
        float e = __expf(v - mx);
        sum += e;
        p[ja - 32] += e * (1.0f - fj);
        p[jb - 32] += e * fj;
      }
    }
    sum += __shfl_xor(sum, 1);
    float other = __shfl_xor(h ? p[0] : p[32], 1);
    float inv = 1.0f / sum;
    __half* prow = &Pws[i * 66];
    if (h == 0) {
      p[32] += other;
      #pragma unroll
      for (int k = 0; k < 33; ++k) prow[k] = __float2half(p[k] * inv);
    } else {
      #pragma unroll
      for (int k = 1; k < 33; ++k) prow[32 + k] = __float2half(p[k] * inv);
    }
  }
  __syncthreads();

  // phase 4: sv/sve contraction + bn_out + pair-sum -> y
  #pragma unroll
  for (int l = 0; l < 8; ++l) {
    int oi = t + l * 256;
    int c = oi >> 7, i = oi & 127;
    const __half* prow = &Pws[i * 66];
    const float* vrow = &vas[c * AA];
    const float* vp = veI + (size_t)c * (AA * 128) + i;
    float sv = 0.f, sve = 0.f;
    #pragma unroll 8
    for (int k = 0; k < 32; ++k) {
      __half2 ph = *(const __half2*)(prow + 2 * k);
      float2 pf = __half22float2(ph);
      sv  += pf.x * vrow[2 * k]       + pf.y * vrow[2 * k + 1];
      sve += pf.x * vp[(2 * k) * 128] + pf.y * vp[(2 * k + 1) * 128];
    }
    float p64 = __half2float(prow[64]);
    sv  += p64 * vrow[64];
    sve += p64 * vp[64 * 128];
    int c2 = g * 16 + c;
    int o0 = 2 * c2;
    float val = og[o0] * RSBN * sv + ob[o0] + og[o0 + 1] * RSBN * sve + ob[o0 + 1];
    y[(((size_t)n * 128 + c2) * 128 + i) * 128 + w] = val;
  }
}

// ---------- G: shift-concat + instance-norm stats ----------
__global__ void k_shift_stats(const float* __restrict__ y, const float* __restrict__ inw,
                              const float* __restrict__ inb, float* __restrict__ xo,
                              float* __restrict__ ss) {
  int nc = blockIdx.x;
  int n = nc >> 7, c = nc & 127;
  int t = threadIdx.x;
  const float* yn = y + (size_t)n * 128 * 16384;
  int sc_ch = c, dh = 0, dw = 0;
  if (c < 10)      { sc_ch = c;      dw = -2; }
  else if (c < 20) { sc_ch = c - 10; dw = 2; }
  else if (c < 30) { sc_ch = c - 20; dh = -2; }
  else if (c < 40) { sc_ch = c - 30; dh = 2; }
  const float* src = yn + (size_t)sc_ch * 16384;
  float* dst = xo + (size_t)nc * 16384;
  float s = 0.f, s2 = 0.f;
  for (int l = 0; l < 64; ++l) {
    int idx = t + l * 256;
    int h = idx >> 7, w = idx & 127;
    int hs = h + dh, ws_ = w + dw;
    float v = 0.f;
    if (hs >= 0 && hs < 128 && ws_ >= 0 && ws_ < 128) v = src[hs * 128 + ws_];
    dst[idx] = v;
    s += v; s2 += v * v;
  }
  __shared__ float rs[256], rs2[256];
  rs[t] = s; rs2[t] = s2;
  __syncthreads();
  for (int st = 128; st > 0; st >>= 1) {
    if (t < st) { rs[t] += rs[t + st]; rs2[t] += rs2[t + st]; }
    __syncthreads();
  }
  if (t == 0) {
    float mean = rs[0] * (1.0f / 16384.0f);
    float var = rs2[0] * (1.0f / 16384.0f) - mean * mean;
    float scale = inw[c] * rsqrtf(var + 1e-5f);
    ss[2 * nc] = scale;
    ss[2 * nc + 1] = inb[c] - mean * scale;
  }
}

// ---------- MFMA GEMM 2: h1 = gelu(W1 . xn), xn normalized during staging ----------
__global__ __launch_bounds__(256) void k_mlp1_mfma(
    const float* __restrict__ xo, const float* __restrict__ ss,
    const short* __restrict__ w1b, short* __restrict__ h1) {
  const int pb = blockIdx.x * 128;
  const int ob = blockIdx.y * 128;
  const int n = blockIdx.z;
  __shared__ short Asm[128 * 40];
  __shared__ short Bsm[128 * 40];
  const int t = threadIdx.x;
  const int lane = t & 63, wv = t >> 6;
  const int wm = wv >> 1, wn = wv & 1;
  const int lr = lane & 15, lk = (lane >> 4) * 8;
  f32x4 acc[4][4];
  #pragma unroll
  for (int a = 0; a < 4; ++a)
    #pragma unroll
    for (int b = 0; b < 4; ++b)
      #pragma unroll
      for (int q = 0; q < 4; ++q) acc[a][b][q] = 0.f;
  const float* X = xo + (size_t)n * 128 * 16384;
  for (int k0 = 0; k0 < 128; k0 += 32) {
    #pragma unroll
    for (int i2 = 0; i2 < 2; ++i2) {
      int u = t + 256 * i2;
      int row = u >> 2, kq = (u & 3) * 8;
      *(bf16x8*)&Asm[row * 40 + kq] = *(const bf16x8*)&w1b[(ob + row) * 128 + k0 + kq];
    }
    #pragma unroll
    for (int i4 = 0; i4 < 4; ++i4) {
      int u = t + 256 * i4;
      int k = u >> 5, p4 = (u & 31) * 4;
      int ch = n * 128 + k0 + k;
      float sc = ss[2 * ch], sh = ss[2 * ch + 1];
      float4 xv = *(const float4*)&X[(size_t)(k0 + k) * 16384 + pb + p4];
      Bsm[(p4 + 0) * 40 + k] = f2b(xv.x * sc + sh);
      Bsm[(p4 + 1) * 40 + k] = f2b(xv.y * sc + sh);
      Bsm[(p4 + 2) * 40 + k] = f2b(xv.z * sc + sh);
      Bsm[(p4 + 3) * 40 + k] = f2b(xv.w * sc + sh);
    }
    __syncthreads();
    bf16x8 af[4], bfr[4];
    #pragma unroll
    for (int mf = 0; mf < 4; ++mf) af[mf] = *(bf16x8*)&Asm[(wm * 64 + mf * 16 + lr) * 40 + lk];
    #pragma unroll
    for (int nf = 0; nf < 4; ++nf) bfr[nf] = *(bf16x8*)&Bsm[(wn * 64 + nf * 16 + lr) * 40 + lk];
    #pragma unroll
    for (int mf = 0; mf < 4; ++mf)
      #pragma unroll
      for (int nf = 0; nf < 4; ++nf)
        acc[mf][nf] = MFMA16(af[mf], bfr[nf], acc[mf][nf]);
    __syncthreads();
  }
  #pragma unroll
  for (int mf = 0; mf < 4; ++mf)
    #pragma unroll
    for (int r = 0; r < 4; ++r) {
      int o = ob + wm * 64 + mf * 16 + (lane >> 4) * 4 + r;
      #pragma unroll
      for (int nf = 0; nf < 4; ++nf) {
        int p = pb + wn * 64 + nf * 16 + lr;
        h1[((size_t)(n * 512 + o)) * 16384 + p] = f2b(gelu_exact(acc[mf][nf][r]));
      }
    }
}

// ---------- MFMA GEMM 3: out = W2 . h1 + identity(y) ----------
__global__ __launch_bounds__(256) void k_mlp2_mfma(
    const short* __restrict__ h1, const short* __restrict__ w2b,
    const float* __restrict__ y, float* __restrict__ out) {
  const int pb = blockIdx.x * 128;
  const int ob = blockIdx.y * 128;
  const int n = blockIdx.z;
  __shared__ short Asm[128 * 40];
  __shared__ short Bsm[128 * 40];
  const int t = threadIdx.x;
  const int lane = t & 63, wv = t >> 6;
  const int wm = wv >> 1, wn = wv & 1;
  const int lr = lane & 15, lk = (lane >> 4) * 8;
  f32x4 acc[4][4];
  #pragma unroll
  for (int a = 0; a < 4; ++a)
    #pragma unroll
    for (int b = 0; b < 4; ++b)
      #pragma unroll
      for (int q = 0; q < 4; ++q) acc[a][b][q] = 0.f;
  const short* H = h1 + (size_t)n * 512 * 16384;
  for (int k0 = 0; k0 < 512; k0 += 32) {
    #pragma unroll
    for (int i2 = 0; i2 < 2; ++i2) {
      int u = t + 256 * i2;
      int row = u >> 2, kq = (u & 3) * 8;
      *(bf16x8*)&Asm[row * 40 + kq] = *(const bf16x8*)&w2b[(ob + row) * 512 + k0 + kq];
    }
    #pragma unroll
    for (int i2 = 0; i2 < 2; ++i2) {
      int u = t + 256 * i2;
      int k = u >> 4, p8 = (u & 15) * 8;
      bf16x8 hv = *(const bf16x8*)&H[(size_t)(k0 + k) * 16384 + pb + p8];
      #pragma unroll
      for (int j = 0; j < 8; ++j) Bsm[(p8 + j) * 40 + k] = hv[j];
    }
    __syncthreads();
    bf16x8 af[4], bfr[4];
    #pragma unroll
    for (int mf = 0; mf < 4; ++mf) af[mf] = *(bf16x8*)&Asm[(wm * 64 + mf * 16 + lr) * 40 + lk];
    #pragma unroll
    for (int nf = 0; nf < 4; ++nf) bfr[nf] = *(bf16x8*)&Bsm[(wn * 64 + nf * 16 + lr) * 40 + lk];
    #pragma unroll
    for (int mf = 0; mf < 4; ++mf)
      #pragma unroll
      for (int nf = 0; nf < 4; ++nf)
        acc[mf][nf] = MFMA16(af[mf], bfr[nf], acc[mf][nf]);
    __syncthreads();
  }
  #pragma unroll
  for (int mf = 0; mf < 4; ++mf)
    #pragma unroll
    for (int r = 0; r < 4; ++r) {
      int o = ob + wm * 64 + mf * 16 + (lane >> 4) * 4 + r;
      #pragma unroll
      for (int nf = 0; nf < 4; ++nf) {
        int p = pb + wn * 64 + nf * 16 + lr;
        size_t base = ((size_t)(n * 128 + o)) * 16384 + p;
        out[base] = acc[mf][nf][r] + y[base];
      }
    }
}

extern "C" void kernel_launch(void* const* d_in, const int* in_sizes, int n_in,
                              void* d_out, int out_size, void* d_ws, size_t ws_size,
                              hipStream_t stream) {
  const float* x        = (const float*)d_in[0];
  const float* w_qkv    = (const float*)d_in[1];
  const float* bn_qkv_g = (const float*)d_in[2];
  const float* bn_qkv_b = (const float*)d_in[3];
  const float* bn_sim_g = (const float*)d_in[4];
  const float* bn_sim_b = (const float*)d_in[5];
  const float* bn_out_g = (const float*)d_in[6];
  const float* bn_out_b = (const float*)d_in[7];
  const float* in_w     = (const float*)d_in[8];
  const float* in_b     = (const float*)d_in[9];
  const float* mlp_w1   = (const float*)d_in[10];
  const float* mlp_w2   = (const float*)d_in[11];
  const float* base_rel = (const float*)d_in[12];
  float* Wp = (float*)d_ws;

  float* relA   = Wp + 0;          // 135,200 (pad 135,424)
  float* relAp  = Wp + 135424;     // 35,360 (pad 35,456)
  float* relATp = Wp + 170880;     // 35,360 (pad 35,456)
  float* veI    = Wp + 206336;     // 133,120 (pad 133,376)
  float* qa     = Wp + 339712;     // 1,064,960
  float* ka     = Wp + 1404672;    // 1,064,960
  float* va     = Wp + 2469632;    // 2,129,920
  float* yb     = Wp + 4599552;    // 4,194,304
  float* ssb    = Wp + 8793856;    // 1,024
  float* xo     = Wp + 8794880;    // 4,194,304
  short* wqb    = (short*)(Wp + 12989184);   // 32,768 shorts (16,384 f)
  short* w1b    = (short*)(Wp + 13005568);   // 65,536 shorts (32,768 f)
  short* w2b    = (short*)(Wp + 13038336);   // 65,536 shorts (32,768 f)
  float* qkv    = Wp + 13071104;   // 8,388,608 (dead after k_down)
  short* h1b    = (short*)(Wp + 13071104);   // 16,777,216 shorts, overlays qkv
  // peak: 21,459,712 floats = 85.8 MB

  k_wbf<<<dim3(256), dim3(256), 0, stream>>>(w_qkv, mlp_w1, mlp_w2, wqb, w1b, w2b);
  k_relA<<<dim3(529), dim3(256), 0, stream>>>(base_rel, relA, relAp, relATp);
  k_vei<<<dim3(520), dim3(256), 0, stream>>>(relA, veI);
  k_qkv_mfma<<<dim3(128, 2, 2), dim3(256), 0, stream>>>(x, wqb, bn_qkv_g, bn_qkv_b, qkv);
  k_down<<<dim3(16640), dim3(256), 0, stream>>>(qkv, qa, ka, va);
  k_attn<<<dim3(2048), dim3(256), 0, stream>>>(qa, ka, va, relAp, relATp, veI,
                                               bn_sim_g, bn_sim_b, bn_out_g, bn_out_b, yb);
  k_shift_stats<<<dim3(256), dim3(256), 0, stream>>>(yb, in_w, in_b, xo, ssb);
  k_mlp1_mfma<<<dim3(128, 4, 2), dim3(256), 0, stream>>>(xo, ssb, w1b, h1b);
  k_mlp2_mfma<<<dim3(128, 1, 2), dim3(256), 0, stream>>>(h1b, w2b, yb, (float*)d_out);
}